// Round 1
// baseline (643.352 us; speedup 1.0000x reference)
//
#include <hip/hip_runtime.h>

// Problem constants
#define HH 2048
#define WW 2048
#define WSK 4095            // real skewed columns
#define WSKP 4096           // padded (col 4095 = dump column; fc reads 0..4094)
#define BLKS 8              // pipelined blocks (CUs)
#define NW  4               // waves per block
#define NT  (NW * 64)       // 256 threads, 1 row/thread
#define KCH 32              // columns per chunk = prefetch depth = unroll
#define NCH (WSKP / KCH)    // 128 chunks
#define FC_IN 1024
#define FC_OUT 10
#define NFLAT ((HH * WW) / FC_IN)

// Inter-block mailbox: ring of {tag,value} u64 per block boundary, in d_out.
// 8 rings x 2048 slots x 8B = 128 KB <= 160 KB out buffer; fc_kernel later
// overwrites every d_out element, so validation is unaffected (same trick as
// the R5/R6 flags). Tag = column+1 (exact match); harness poison 0xAA..,
// memset 0, and fc's float outputs (bit patterns >= ~1e9 or huge) never
// collide with tags <= 4096.
#define MRING 2048

// tanh(x) = 1 - 2/(exp2(x*2/ln2)+1); caller passes pre-scaled xs = x*2/ln2.
__device__ __forceinline__ float tanh_pre(float xs) {
  float e = __builtin_amdgcn_exp2f(xs);
  float r = __builtin_amdgcn_rcpf(e + 1.0f);
  return __builtin_fmaf(-2.0f, r, 1.0f);
}

// Full-wave shift-up-by-1 via DPP wave_shr:1 (verified R5: exact absmax).
// result[l] = src[l-1], result[0] = old.
__device__ __forceinline__ float wave_shr1(float src, float old) {
  int r = __builtin_amdgcn_update_dpp(
      __builtin_bit_cast(int, old), __builtin_bit_cast(int, src),
      0x138 /*wave_shr:1*/, 0xF, 0xF, false);
  return __builtin_bit_cast(float, r);
}

// inp[c*HH+r] = S*(w*img[r][c-r] + b_in + b_state), bias-only off-image.
__global__ __launch_bounds__(256) void skew_kernel(
    const float* __restrict__ img, const float* __restrict__ w_in,
    const float* __restrict__ b_in, const float* __restrict__ b_state,
    float* __restrict__ inp) {
  const float S = 2.88539008177792681472f;   // 2/ln(2)
  const float ws = w_in[0] * S;
  const float Cs = (b_in[0] + b_state[0]) * S;
  int gid = blockIdx.x * 256 + threadIdx.x;  // gid = c*HH + r
  int r = gid & (HH - 1);
  int c = gid >> 11;
  int idx = c - r;
  float v = Cs;
  if ((unsigned)idx < (unsigned)WW) v = fmaf(ws, img[(size_t)r * WW + idx], Cs);
  inp[gid] = v;
}

// 8-block x 4-wave wavefront-pipelined scan, 1 row/thread.
// R7 changes vs R6 (556 us total / 438 us scan; theory: per-epoch sync costs
// serialized by the barrier dominate the unexplained ~140 cyc/col):
//  * Inter-block handoff = self-validating {tag,value} u64 mailbox with
//    RELAXED agent atomics only. No acquire/release -> no buffer_inv, no L2
//    writeback ordering of the 32MB acts stream, no vmcnt drains.
//  * Consumer prefetches the next chunk's 32 boundary words one chunk ahead;
//    steady-state LLC latency hides under the 32-column compute.
//  * Producer (wave NW-1) publishes per column, REPLACING its dead ring
//    write (ring[.][NW-1] was never read) -> its loop issue count ~unchanged.
//  * Exact-tag back-pressure (1 probe/chunk vs downstream block's beacon)
//    makes ring wrap safe under any scheduling skew; free in steady state.
// Ring semantics (verified R2-R5): ring[e&1][w][i] = wave w's h AFTER column
// c0+i-1; slot 0 at chunk start, slot i+1 after column i.
__global__ __launch_bounds__(NT) void scan_kernel(
    const float* __restrict__ w_state, const float* __restrict__ inp,
    float* __restrict__ acts, unsigned long long* __restrict__ mbox) {
  const int t = threadIdx.x;
  const int wv = t >> 6;
  const int lane = t & 63;
  const int blk = blockIdx.x;
  const int r = blk * NT + t;                // global row (1 per thread)

  const float S = 2.88539008177792681472f;
  const float k0s = w_state[0] * S;
  const float k1s = w_state[1] * S;

  __shared__ float ring[2][NW][KCH];

  float h = 0.0f;
  const float* colp_in = inp + r;
  float* colp_out = acts + r;

  // Prime prefetch registers with chunk 0 (whole chunk).
  float pf[KCH];
  #pragma unroll
  for (int d = 0; d < KCH; ++d) pf[d] = colp_in[(size_t)d * HH];

  // Prime mailbox prefetch for chunk 0 (consumer wave only).
  unsigned long long praw = 0;
  if (wv == 0 && blk > 0 && lane < KCH) {
    unsigned long long* mb_up = mbox + (size_t)(blk - 1) * MRING;
    int cl = lane - 1;
    praw = __hip_atomic_load(&mb_up[cl & (MRING - 1)], __ATOMIC_RELAXED,
                             __HIP_MEMORY_SCOPE_AGENT);
  }

  for (int e = 0; e < NCH + NW - 1; ++e) {
    const int ch = e - wv;
    if (0 <= ch && ch < NCH) {
      const int c0 = ch * KCH;

      // Gather this chunk's 32 boundary values into lanes 0..31 of bvec:
      // lane i = neighbor-row h AFTER column c0+i-1.
      float bvec;
      if (wv == 0) {
        bvec = 0.0f;
        if (blk > 0) {
          unsigned long long* mb_up = mbox + (size_t)(blk - 1) * MRING;
          const int cl = c0 + lane - 1;
          const bool need = (lane < KCH) && (cl >= 0);
          const unsigned want = (unsigned)(cl + 1);
          unsigned long long raw = praw;
          // Validate the prefetched words; retry-load on mismatch (rare:
          // producer runs ~4 epochs ahead in steady state).
          while (!__all((!need) || ((unsigned)(raw >> 32) == want))) {
            __builtin_amdgcn_s_sleep(1);
            if (need)
              raw = __hip_atomic_load(&mb_up[cl & (MRING - 1)],
                                      __ATOMIC_RELAXED,
                                      __HIP_MEMORY_SCOPE_AGENT);
          }
          if (need) bvec = __builtin_bit_cast(float, (unsigned)raw);
          // Prefetch next chunk's boundary words; in flight across this
          // chunk's 32-column compute.
          if (lane < KCH)
            praw = __hip_atomic_load(&mb_up[(cl + KCH) & (MRING - 1)],
                                     __ATOMIC_RELAXED,
                                     __HIP_MEMORY_SCOPE_AGENT);
        }
      } else {
        // Written entirely by wave wv-1 during the previous epoch.
        bvec = ring[(e & 1) ^ 1][wv - 1][lane & (KCH - 1)];
      }
      if (lane == 63 && wv != NW - 1) ring[e & 1][wv][0] = h;

      // Back-pressure: before (re)using ring slots, ensure the downstream
      // block consumed the old tenants. Exact-tag check vs its beacon; the
      // ~1920-column margin (>= 60 chunks) dwarfs the ~4-chunk steady lag,
      // so this never spins in practice but removes the wrap deadlock.
      if (wv == NW - 1 && blk + 1 < BLKS) {
        const int cmax = c0 + KCH - 1;
        if (cmax >= MRING) {
          unsigned long long* mb_dn = mbox + (size_t)(blk + 1) * MRING;
          const int cref = cmax - (MRING - 128);
          const unsigned wantt = (unsigned)(cref + 1);
          if (lane == 63) {
            while ((unsigned)(__hip_atomic_load(&mb_dn[cref & (MRING - 1)],
                       __ATOMIC_RELAXED, __HIP_MEMORY_SCOPE_AGENT) >> 32)
                   != wantt)
              __builtin_amdgcn_s_sleep(8);
          }
        }
      }

      // Next-chunk prefetch base (clamped reload at final chunk, unused).
      const int cb = (ch + 1 < NCH ? ch + 1 : ch) * KCH;
      unsigned long long* mb_my = mbox + (size_t)blk * MRING;

      #pragma unroll
      for (int cc = 0; cc < KCH; ++cc) {
        float cur = pf[cc];
        pf[cc] = colp_in[(size_t)(cb + cc) * HH];

        // Boundary value for lane 0, off the critical chain (SALU readlane).
        float pv = __builtin_bit_cast(float,
            __builtin_amdgcn_readlane(__builtin_bit_cast(int, bvec), cc));
        float prev = wave_shr1(h, pv);   // prev[l]=h[l-1], prev[0]=pv

        h = tanh_pre(fmaf(k0s, prev, fmaf(k1s, h, cur)));

        if (lane == 63) {
          if (wv != NW - 1) {
            if (cc + 1 < KCH) ring[e & 1][wv][cc + 1] = h;
          } else {
            // Publish {tag,value}: single relaxed agent atomic (sc-flagged
            // dwordx2 to the coherent point). Self-validating: no fence.
            unsigned long long pack =
                ((unsigned long long)(unsigned)(c0 + cc + 1) << 32) |
                (unsigned long long)__builtin_bit_cast(unsigned, h);
            __hip_atomic_store(&mb_my[(c0 + cc) & (MRING - 1)], pack,
                               __ATOMIC_RELAXED, __HIP_MEMORY_SCOPE_AGENT);
          }
        }
        colp_out[(size_t)(c0 + cc) * HH] = h;   // unconditional (4095 = dump)
      }
    }
    // LDS-only barrier: rotates the ring double-buffer WITHOUT draining
    // vmcnt, so next-chunk prefetches survive the epoch boundary.
    asm volatile("s_waitcnt lgkmcnt(0)\n\ts_barrier" ::: "memory");
  }
}

// Unskew + FC, coalesced: one block per 16 acts-rows (32 flat rows).
// acts[col][r0..r0+15] tiles are loaded as 64B row-segments (every fetched
// line fully used, vs the old 1-of-16 gather), transposed through LDS, and
// dotted against LDS-staged fc_w. flat[i][k] = acts[(i>>1)+(i&1)*1024+k][i>>1].
#define FCR 16                 // acts rows per block
#define FCCH 256               // column chunk staged in LDS
#define FCT 256                // threads per block

__global__ __launch_bounds__(FCT) void fc_kernel(
    const float* __restrict__ acts, const float* __restrict__ fc_w,
    const float* __restrict__ fc_b, float* __restrict__ out) {
  __shared__ float fcw[FC_OUT * FC_IN];        // 40 KB
  __shared__ float tile[FCCH][FCR + 1];        // 17.4 KB, +1 pad vs banks

  const int tid = threadIdx.x;
  const int bb = blockIdx.x;
  const int r0 = bb * FCR;

  for (int i = tid; i < FC_OUT * FC_IN; i += FCT) fcw[i] = fc_w[i];

  const int il = tid >> 3;                 // flat-row local index 0..31
  const int cs = tid & 7;                  // column slice 0..7
  const int rloc = il >> 1;                // local acts row 0..15
  const int koff = (r0 + rloc) + ((il & 1) << 10);   // k = col - koff

  const int lrr = tid & 15;                // staging: row
  const int lco = tid >> 4;                // staging: col 0..15

  float acc[FC_OUT];
  #pragma unroll
  for (int j = 0; j < FC_OUT; ++j) acc[j] = 0.0f;

  __syncthreads();

  const int cend = r0 + FCR - 1 + 2047;    // last needed col = r0 + 2062
  for (int cb = r0; cb <= cend; cb += FCCH) {
    // Stage tile[cc][rr] = acts[(cb+cc)*HH + r0+rr], 16 consecutive floats
    // per (col) -> 64B coalesced segments.
    #pragma unroll
    for (int s = 0; s < FCCH / 16; ++s) {
      int cc = s * 16 + lco;
      int col = cb + cc;
      int colc = col < WSK ? col : (WSK - 1);  // clamp; predicate guards use
      tile[cc][lrr] = acts[(size_t)colc * HH + r0 + lrr];
    }
    __syncthreads();

    // Each thread: its flat row, cols == cs (mod 8) of this chunk.
    #pragma unroll 4
    for (int tt = 0; tt < FCCH / 8; ++tt) {
      int cc = tt * 8 + cs;
      int k = cb + cc - koff;
      if (0 <= k && k < FC_IN) {
        float v = tile[cc][rloc];
        #pragma unroll
        for (int j = 0; j < FC_OUT; ++j)
          acc[j] = fmaf(v, fcw[j * FC_IN + k], acc[j]);
      }
    }
    __syncthreads();
  }

  // Reduce the 8 column-slice partials (8 consecutive lanes, wave-aligned).
  #pragma unroll
  for (int j = 0; j < FC_OUT; ++j) {
    acc[j] += __shfl_down(acc[j], 4, 8);
    acc[j] += __shfl_down(acc[j], 2, 8);
    acc[j] += __shfl_down(acc[j], 1, 8);
  }
  if (cs == 0) {
    const int i = bb * 32 + il;              // flat row
    #pragma unroll
    for (int j = 0; j < FC_OUT; ++j) out[i * FC_OUT + j] = acc[j] + fc_b[j];
  }
}

extern "C" void kernel_launch(void* const* d_in, const int* in_sizes, int n_in,
                              void* d_out, int out_size, void* d_ws, size_t ws_size,
                              hipStream_t stream) {
  const float* x       = (const float*)d_in[0];
  const float* w_in    = (const float*)d_in[1];
  const float* b_in    = (const float*)d_in[2];
  const float* w_state = (const float*)d_in[3];
  const float* b_state = (const float*)d_in[4];
  const float* fc_w    = (const float*)d_in[5];
  const float* fc_b    = (const float*)d_in[6];
  float* out = (float*)d_out;
  float* buf = (float*)d_ws;   // WSKP*HH*4 = 32 MiB: inp -> acts in-place

  // Mailboxes live in d_out (128 KB of its 160 KB): scan writes {tag,value}
  // words there, fc_kernel later overwrites EVERY d_out element with real
  // outputs, so validation is unaffected. Poison/memset/fc-float bit patterns
  // never equal an expected tag, so rings are correctly "reset" every launch.
  unsigned long long* mbox = (unsigned long long*)d_out;

  skew_kernel<<<(WSKP * HH) / 256, 256, 0, stream>>>(x, w_in, b_in, b_state, buf);
  scan_kernel<<<BLKS, NT, 0, stream>>>(w_state, buf, buf, mbox);
  fc_kernel<<<HH / FCR, FCT, 0, stream>>>(buf, fc_w, fc_b, out);
}